// Round 8
// baseline (182.486 us; speedup 1.0000x reference)
//
#include <hip/hip_runtime.h>

// ---------------------------------------------------------------------------
// GAT (2-layer, dense mask) on gfx950 — R22.
// R21 post-mortem: xA pre-pack neutral (172.2 vs 170.4) -> reverted; gemm1's
// limiter is neither gemm arithmetic (R21) nor pack instruction mix (R18).
// Remaining axis: pack PARALLELISM (512 blocks, 8x256B in flight/wave; R14
// counters: Occ 17, HBM 14.5%, 1 TB/s = latency-bound streaming).
// R22: (1) adj-pack 512 -> 2048 blocks (4x load streams in flight);
//      (2) fuse att2+final -> k_att2f: 256 blocks x 16 rows, 4 waves cover
//          disjoint j-quarters, 4KB LDS reduce + 1 barrier, in-block ELU +
//          row-log-softmax (16-lane shfl), direct out write. Deletes one
//          launch + the 4.25 MB pnum2/pden2 round-trip.
// De-confound plan: on regression, revert (2) first.
// ---------------------------------------------------------------------------

typedef _Float16 h2 __attribute__((ext_vector_type(2)));
typedef _Float16 half8 __attribute__((ext_vector_type(8)));
typedef __attribute__((ext_vector_type(4))) float f32x4;
typedef unsigned long long u64;
typedef unsigned short u16;
typedef unsigned int u32;

__device__ __forceinline__ u16 f2h(float f){
  union { _Float16 h; u16 u; } c; c.h = (_Float16)f; return c.u;
}
__device__ __forceinline__ h2 u2h2(u32 u){ union { u32 u; h2 h; } c; c.u = u; return c.h; }
__device__ __forceinline__ u32 h22u(h2 h){ union { u32 u; h2 h; } c; c.h = h; return c.u; }
__device__ __forceinline__ half8 pk2h8(uint4 v){ union { uint4 u; half8 h; } c; c.u = v; return c.h; }

__device__ __forceinline__ void async16(void* lds, const void* g){
  __builtin_amdgcn_global_load_lds((const __attribute__((address_space(1))) u32*)g,
                                   (__attribute__((address_space(3))) u32*)lds, 16, 0, 0);
}
__device__ __forceinline__ void async4(void* lds, const void* g){
  __builtin_amdgcn_global_load_lds((const __attribute__((address_space(1))) u32*)g,
                                   (__attribute__((address_space(3))) u32*)lds, 4, 0, 0);
}

// ===== K0: pack W f32 -> f16 B-layout [h][fgb(64)][o(64)][q(8)] ============
__global__ __launch_bounds__(256) void k_wpack(const float* __restrict__ W,
                                               u16* __restrict__ Wb16){
  int t = blockIdx.x * 256 + threadIdx.x;   // 0..32767 = 8 h x 64 fgb x 64 o
  int o   = t & 63;
  int fgb = (t >> 6) & 63;
  int h   = t >> 12;
  const float* src = W + ((size_t)h * 512 + fgb * 8) * 64 + o;
  u32 pk[4];
  #pragma unroll
  for (int p = 0; p < 4; ++p)
    pk[p] = (u32)f2h(src[(2 * p) * 64]) | ((u32)f2h(src[(2 * p + 1) * 64]) << 16);
  *(uint4*)(Wb16 + ((size_t)h * 4096 + fgb * 64 + o) * 8) = *(uint4*)pk;
}

// ===== K1: Wh = x @ W[h] (B-frags from global Wb16) + tables + whB,        =
// =====     plus block-specialized adj bitmask pack (bx >= 64, 2048 blocks) =
__global__ __launch_bounds__(256) void k_gemm1(const float* __restrict__ x,
                                               const u16* __restrict__ Wb16,
                                               const float* __restrict__ av,
                                               const int* __restrict__ adj,
                                               u16* __restrict__ whB,
                                               u64* __restrict__ bits_t,
                                               float* __restrict__ r1,
                                               u16* __restrict__ e21h, u16* __restrict__ e202h){
  __shared__ u16 tr[4096];                 // 8 KB transpose buffer (only LDS)
  int h    = blockIdx.y;
  int bx   = blockIdx.x;
  int tid  = threadIdx.x;
  int lane = tid & 63;
  int wv   = tid >> 6;

  if (bx >= 64){
    // ---- adj-pack slice: 2048 blocks, 128 uids each (4x in-flight) ----
    int B2 = h * 256 + (bx - 64);          // 0..2047
    int uid0 = B2 * 128 + wv * 32;
    for (int k = 0; k < 32; k += 8){
      int v[8];
      #pragma unroll
      for (int q = 0; q < 8; ++q){
        int uid = uid0 + k + q;
        v[q] = adj[(size_t)(uid >> 6) * 4096 + ((uid & 63) << 6) + lane];
      }
      u64 m[8];
      #pragma unroll
      for (int q = 0; q < 8; ++q) m[q] = __ballot(v[q] != 0);
      if (lane == 0){
        #pragma unroll
        for (int q = 0; q < 8; ++q){
          int uid = uid0 + k + q;
          bits_t[(size_t)(uid & 63) * 4096 + (uid >> 6)] = m[q];
        }
      }
    }
    return;
  }

  // ---- gemm path ----
  int row16 = lane & 15, grp = lane >> 4;
  int n0 = bx * 64;
  int n0w = n0 + wv * 16;
  const u16* wb = Wb16 + (size_t)h * 32768;

  f32x4 acc[4] = {};
  #pragma unroll 4
  for (int ks = 0; ks < 16; ++ks){
    int fgb = ks * 4 + grp;
    const float* xs = x + (size_t)(n0w + row16) * 512 + fgb * 8;
    float4 xv0 = ((const float4*)xs)[0];
    float4 xv1 = ((const float4*)xs)[1];
    u32 ax[4];
    ax[0] = (u32)f2h(xv0.x) | ((u32)f2h(xv0.y) << 16);
    ax[1] = (u32)f2h(xv0.z) | ((u32)f2h(xv0.w) << 16);
    ax[2] = (u32)f2h(xv1.x) | ((u32)f2h(xv1.y) << 16);
    ax[3] = (u32)f2h(xv1.z) | ((u32)f2h(xv1.w) << 16);
    half8 af = pk2h8(*(uint4*)ax);
    #pragma unroll
    for (int nt = 0; nt < 4; ++nt){
      half8 bf = *(const half8*)(wb + ((size_t)fgb * 64 + nt * 16 + row16) * 8);
      acc[nt] = __builtin_amdgcn_mfma_f32_16x16x32_f16(af, bf, acc[nt], 0, 0, 0);
    }
  }
  // ---- scale-free score tables ----
  float a1v[4], a2v[4];
  #pragma unroll
  for (int nt = 0; nt < 4; ++nt){
    a1v[nt] = av[h * 128 + nt * 16 + row16];
    a2v[nt] = av[h * 128 + 64 + nt * 16 + row16];
  }
  #pragma unroll
  for (int r = 0; r < 4; ++r){
    float p1 = acc[0][r]*a1v[0] + acc[1][r]*a1v[1] + acc[2][r]*a1v[2] + acc[3][r]*a1v[3];
    float p2 = acc[0][r]*a2v[0] + acc[1][r]*a2v[1] + acc[2][r]*a2v[2] + acc[3][r]*a2v[3];
    #pragma unroll
    for (int d = 1; d < 16; d <<= 1){ p1 += __shfl_xor(p1, d, 64); p2 += __shfl_xor(p2, d, 64); }
    if (row16 == 0){
      int idx = h * 4096 + n0w + grp * 4 + r;
      r1[idx]    = __expf(-0.8f * p1);     // row scale e^{-0.8 s1}
      e21h[idx]  = f2h(__expf(p2));
      e202h[idx] = f2h(__expf(0.2f * p2));
    }
  }
  // ---- whB f16 pack via LDS transpose ----
  #pragma unroll
  for (int nt = 0; nt < 4; ++nt)
    #pragma unroll
    for (int r = 0; r < 4; ++r){
      int jl = wv * 16 + grp * 4 + r;
      int o  = nt * 16 + row16;
      tr[((jl >> 3) * 64 + o) * 8 + (jl & 7)] = f2h(acc[nt][r]);
    }
  __syncthreads();
  u16* dst = whB + (size_t)h * 262144 + (size_t)n0 * 64;
  #pragma unroll
  for (int q = 0; q < 2; ++q)
    *(uint4*)(dst + (tid * 2 + q) * 8) = *(const uint4*)(tr + (tid * 2 + q) * 8);
}

// ===== K2: layer-1 attention (LDS dbuf, KVBLK=128, f16 packed w-gen) =======
__global__ __launch_bounds__(256) void k_att1(const u16* __restrict__ whB,
                                              const u64* __restrict__ bits_t,
                                              const float* __restrict__ r1,
                                              const u16* __restrict__ e21h, const u16* __restrict__ e202h,
                                              u16* __restrict__ pnum, float* __restrict__ pden){
  __shared__ u16  smB[2][8192];            // 128 j x 64 o f16, [j/8][o][j&7]
  __shared__ u32  smT[2][2][64];           // staged f16 tables (256 B each)
  __shared__ u32  smLut[4];
  int h     = blockIdx.y;
  int iblk  = blockIdx.x;
  int split = blockIdx.z;
  int lane = threadIdx.x & 63;
  int wv   = threadIdx.x >> 6;
  int tid  = threadIdx.x;
  int row16 = lane & 15, grp = lane >> 4;
  if (threadIdx.x < 4)
    smLut[threadIdx.x] = ((threadIdx.x & 1) ? 0xFFFFu : 0u) | ((threadIdx.x & 2) ? 0xFFFF0000u : 0u);
  int i = iblk * 64 + wv * 16 + row16;
  int hoff = h * 4096;
  u32 rb = (u32)f2h(r1[hoff + i]); rb |= rb << 16;
  h2 rr = u2h2(rb);
  const u16* whBh = whB + (size_t)h * 262144;
  int jbeg = split * 1024;

  half8 bden;                              // ones-column B frag for den
  {
    u32 z[4] = {0,0,0,0};
    if (row16 == 0){ z[0]=0x3C003C00u; z[1]=0x3C003C00u; z[2]=0x3C003C00u; z[3]=0x3C003C00u; }
    bden = pk2h8(*(uint4*)z);
  }

  auto stage = [&](int bb, int j0){
    // 16 KB B-tile: 4 x async16 per thread, fully contiguous
    const char* g = (const char*)whBh + (size_t)j0 * 128 + tid * 16;
    char* l = (char*)(&smB[bb][0]) + tid * 16;
    #pragma unroll
    for (int k = 0; k < 4; ++k)
      async16(l + k * 4096, g + k * 4096);
    // 256 B per table = 128 f16 (exactly one KVBLK)
    if (wv == 0)      async4(&smT[bb][0][0], (const char*)(e21h  + hoff + j0) + lane * 4);
    else if (wv == 1) async4(&smT[bb][1][0], (const char*)(e202h + hoff + j0) + lane * 4);
  };

  f32x4 acc[4] = {};
  f32x4 accden = {};
  stage(0, jbeg);
  for (int c = 0; c < 8; ++c){
    int bb = c & 1;
    u64 mrow0 = bits_t[(size_t)(split * 16 + c * 2)     * 4096 + i];   // coalesced
    u64 mrow1 = bits_t[(size_t)(split * 16 + c * 2 + 1) * 4096 + i];
    __syncthreads();                       // buf bb staged; buf bb^1 free
    if (c < 7) stage(bb ^ 1, jbeg + (c + 1) * 128);
    #pragma unroll
    for (int ks = 0; ks < 4; ++ks){
      uint4 e1q = *(const uint4*)((const char*)&smT[bb][0][0] + ks * 64 + grp * 16);
      uint4 e2q = *(const uint4*)((const char*)&smT[bb][1][0] + ks * 64 + grp * 16);
      u32 es[4] = {e1q.x, e1q.y, e1q.z, e1q.w};
      u32 gs[4] = {e2q.x, e2q.y, e2q.z, e2q.w};
      const u16* bbase = &smB[bb][(ks * 4 + grp) * 512];
      half8 bf0 = *(const half8*)(bbase + (0 * 16 + row16) * 8);
      half8 bf1 = *(const half8*)(bbase + (1 * 16 + row16) * 8);
      half8 bf2 = *(const half8*)(bbase + (2 * 16 + row16) * 8);
      half8 bf3 = *(const half8*)(bbase + (3 * 16 + row16) * 8);
      u64 mrow = (ks < 2) ? mrow0 : mrow1;
      u32 mb = ((u32)(mrow >> ((ks & 1) * 32)) >> (grp * 8)) & 0xffu;
      u32 pk[4];
      #pragma unroll
      for (int t2i = 0; t2i < 4; ++t2i){
        h2 w = __builtin_elementwise_max(u2h2(es[t2i]), rr * u2h2(gs[t2i]));
        pk[t2i] = h22u(w) & smLut[(mb >> (2 * t2i)) & 3u];
      }
      half8 af = pk2h8(*(uint4*)pk);
      acc[0] = __builtin_amdgcn_mfma_f32_16x16x32_f16(af, bf0, acc[0], 0, 0, 0);
      acc[1] = __builtin_amdgcn_mfma_f32_16x16x32_f16(af, bf1, acc[1], 0, 0, 0);
      acc[2] = __builtin_amdgcn_mfma_f32_16x16x32_f16(af, bf2, acc[2], 0, 0, 0);
      acc[3] = __builtin_amdgcn_mfma_f32_16x16x32_f16(af, bf3, acc[3], 0, 0, 0);
      accden = __builtin_amdgcn_mfma_f32_16x16x32_f16(af, bden, accden, 0, 0, 0);
    }
  }

  #pragma unroll
  for (int r4 = 0; r4 < 4; ++r4){
    int n = iblk * 64 + wv * 16 + grp * 4 + r4;
    if (row16 == 0)
      pden[((size_t)split * 8 + h) * 4096 + n] = accden[r4];
    u16* dst = pnum + ((size_t)split * 4096 + n) * 512 + h * 64 + row16;
    #pragma unroll
    for (int nt = 0; nt < 4; ++nt)
      dst[nt * 16] = f2h(acc[nt][r4]);
  }
}

// ===== K3: combine + Who = h @ Wout + layer-2 tables (4 rows/block) ========
__global__ __launch_bounds__(256) void k_gemm2(const u16* __restrict__ pnum,
                                               const float* __restrict__ pden,
                                               const float* __restrict__ Wout,
                                               const float* __restrict__ aout,
                                               u16* __restrict__ whoB,
                                               float* __restrict__ r1o,
                                               u16* __restrict__ e21oh, u16* __restrict__ e202oh){
  __shared__ float hrowf[4][512];             // 8 KB combined+elu rows (f32)
  int n0  = blockIdx.x * 4;
  int tid = threadIdx.x;
  // ---- phase A: combine 4 splits + ELU, 64 threads per row ----
  {
    int nn = tid >> 6;                        // row 0..3
    int fc = tid & 63;                        // f-chunk 0..63
    int f0 = fc * 8;
    int hh = fc >> 3;                         // head = f0/64
    int n  = n0 + nn;
    float v[8] = {0.f,0.f,0.f,0.f,0.f,0.f,0.f,0.f};
    float d = 0.f;
    #pragma unroll
    for (int s = 0; s < 4; ++s){
      uint4 raw = *(const uint4*)(pnum + ((size_t)s * 4096 + n) * 512 + f0);
      u32 rw[4] = {raw.x, raw.y, raw.z, raw.w};
      #pragma unroll
      for (int q = 0; q < 4; ++q){
        h2 dh = u2h2(rw[q]);
        v[q * 2]     += (float)dh.x;
        v[q * 2 + 1] += (float)dh.y;
      }
      d += pden[((size_t)s * 8 + hh) * 4096 + n];
    }
    float dinv = 1.f / d;
    #pragma unroll
    for (int k = 0; k < 8; ++k){
      float val = v[k] * dinv;
      hrowf[nn][f0 + k] = val > 0.f ? val : (__expf(val) - 1.f);
    }
  }
  __syncthreads();
  // ---- phase B: who[n][c] via K-split dot (Wout stays in L1: 32 KB) ----
  int rl = tid >> 6;                          // row 0..3
  int kq = (tid >> 4) & 3;                    // K-quarter 0..3
  int c  = tid & 15;                          // out col 0..15
  int n  = n0 + rl;
  const float* hr = &hrowf[rl][kq * 128];
  const float* wp = Wout + (size_t)(kq * 128) * 16 + c;
  float a0 = 0.f, a1 = 0.f;
  #pragma unroll 16
  for (int f = 0; f < 128; f += 2){
    a0 += hr[f]     * wp[f * 16];
    a1 += hr[f + 1] * wp[f * 16 + 16];
  }
  float acc = a0 + a1;
  acc += __shfl_xor(acc, 16, 64);             // reduce over kq
  acc += __shfl_xor(acc, 32, 64);
  int lane = tid & 63;
  if ((lane >> 4) == 0)
    whoB[((size_t)(n >> 3) * 16 + c) * 8 + (n & 7)] = f2h(acc);
  float p1 = acc * aout[c], p2 = acc * aout[16 + c];
  #pragma unroll
  for (int d = 1; d < 16; d <<= 1){ p1 += __shfl_xor(p1, d, 64); p2 += __shfl_xor(p2, d, 64); }
  if (lane == 0){
    r1o[n]    = __expf(-0.8f * p1);
    e21oh[n]  = f2h(__expf(p2));
    e202oh[n] = f2h(__expf(0.2f * p2));
  }
}

// ===== K4: layer-2 attention FUSED with elu+log_softmax ====================
// 256 blocks x 16 rows; 4 waves cover disjoint j-quarters (16 chunks each);
// LDS reduce (4KB) + 1 barrier; in-block row softmax via 16-lane shfl.
__global__ __launch_bounds__(256) void k_att2f(const u16* __restrict__ whoB,
                                               const u64* __restrict__ bits_t,
                                               const float* __restrict__ r1o,
                                               const u16* __restrict__ e21oh, const u16* __restrict__ e202oh,
                                               float* __restrict__ out){
  __shared__ u32 smLut[4];
  __shared__ float rnum[4][256];
  __shared__ float rden[4][16];
  int iblk = blockIdx.x;                      // 0..255, 16 rows each
  int tid  = threadIdx.x;
  int lane = tid & 63;
  int wv   = tid >> 6;
  int row16 = lane & 15, grp = lane >> 4;
  if (tid < 4)
    smLut[tid] = ((tid & 1) ? 0xFFFFu : 0u) | ((tid & 2) ? 0xFFFF0000u : 0u);
  __syncthreads();
  int i = iblk * 16 + row16;                  // mask row (same 16 rows all waves)
  u32 rb = (u32)f2h(r1o[i]); rb |= rb << 16;
  h2 rr = u2h2(rb);
  half8 bden;
  {
    u32 z[4] = {0,0,0,0};
    if (row16 == 0){ z[0]=0x3C003C00u; z[1]=0x3C003C00u; z[2]=0x3C003C00u; z[3]=0x3C003C00u; }
    bden = pk2h8(*(uint4*)z);
  }

  f32x4 acc = {};
  f32x4 accden = {};
  for (int k = 0; k < 16; ++k){
    int chunk = wv * 16 + k;                  // this wave's j-chunk 0..63
    int j0 = chunk * 64;
    u64 mrow = bits_t[(size_t)chunk * 4096 + i];
    #pragma unroll
    for (int ks = 0; ks < 2; ++ks){
      int sb = (j0 >> 3) + ks * 4 + grp;
      half8 bf = *(const half8*)(whoB + ((size_t)sb * 16 + row16) * 8);
      uint4 e1q = *(const uint4*)(e21oh  + j0 + ks * 32 + grp * 8);
      uint4 e2q = *(const uint4*)(e202oh + j0 + ks * 32 + grp * 8);
      u32 es[4] = {e1q.x, e1q.y, e1q.z, e1q.w};
      u32 gs[4] = {e2q.x, e2q.y, e2q.z, e2q.w};
      u32 mb = ((u32)(mrow >> (ks * 32)) >> (grp * 8)) & 0xffu;
      u32 pk[4];
      #pragma unroll
      for (int t2i = 0; t2i < 4; ++t2i){
        h2 w = __builtin_elementwise_max(u2h2(es[t2i]), rr * u2h2(gs[t2i]));
        pk[t2i] = h22u(w) & smLut[(mb >> (2 * t2i)) & 3u];
      }
      half8 af = pk2h8(*(uint4*)pk);
      acc    = __builtin_amdgcn_mfma_f32_16x16x32_f16(af, bf, acc, 0, 0, 0);
      accden = __builtin_amdgcn_mfma_f32_16x16x32_f16(af, bden, accden, 0, 0, 0);
    }
  }
  // cross-wave reduce: D layout row = grp*4+r4 (0..15), col = row16
  #pragma unroll
  for (int r4 = 0; r4 < 4; ++r4){
    rnum[wv][(grp * 4 + r4) * 16 + row16] = acc[r4];
    if (row16 == 0) rden[wv][grp * 4 + r4] = accden[r4];
  }
  __syncthreads();
  int r = tid >> 4, c = tid & 15;             // 256 threads = 16x16 tile
  float num = rnum[0][r * 16 + c] + rnum[1][r * 16 + c]
            + rnum[2][r * 16 + c] + rnum[3][r * 16 + c];
  float den = rden[0][r] + rden[1][r] + rden[2][r] + rden[3][r];
  float v = num / den;
  v = v > 0.f ? v : (__expf(v) - 1.f);
  float m = v;
  #pragma unroll
  for (int d = 1; d < 16; d <<= 1) m = fmaxf(m, __shfl_xor(m, d, 64));
  float es = __expf(v - m), ss = es;
  #pragma unroll
  for (int d = 1; d < 16; d <<= 1) ss += __shfl_xor(ss, d, 64);
  out[(size_t)(iblk * 16 + r) * 16 + c] = v - m - __logf(ss);
}

// ---------------------------------------------------------------------------
extern "C" void kernel_launch(void* const* d_in, const int* in_sizes, int n_in,
                              void* d_out, int out_size, void* d_ws, size_t ws_size,
                              hipStream_t stream){
  (void)in_sizes; (void)n_in; (void)out_size; (void)ws_size;
  const float* x    = (const float*)d_in[0];
  const int*   adj  = (const int*)d_in[1];
  const float* W    = (const float*)d_in[2];
  const float* av   = (const float*)d_in[3];
  const float* Wout = (const float*)d_in[4];
  const float* aout = (const float*)d_in[5];
  float* out = (float*)d_out;
  char* ws = (char*)d_ws;

  u64*  bits_t  = (u64*)(ws + 0x0000000);        // 2 MB [64][4096]
  u16*  whB     = (u16*)(ws + 0x0200000);        // 4 MB f16 [8][j/8][o][8]
  float* r1     = (float*)(ws + 0x0600000);      // 128 KB
  u16*  e21h    = (u16*)(ws + 0x0620000);        // 64 KB f16
  u16*  e202h   = (u16*)(ws + 0x0630000);        // 64 KB f16
  u16*  pnum1   = (u16*)(ws + 0x0680000);        // 16 MB f16 [4][4096][512]
  float* pden1  = (float*)(ws + 0x1680000);      // 512 KB [4][8][4096]
  u16*  whoB    = (u16*)(ws + 0x1700000);        // 128 KB f16
  float* r1o    = (float*)(ws + 0x1720000);      // 16 KB
  u16*  e21oh   = (u16*)(ws + 0x1724000);        // 8 KB f16
  u16*  e202oh  = (u16*)(ws + 0x1726000);        // 8 KB f16
  // Wb16 aliases the (now-unused) pnum2 region: written by k_wpack, read by
  // k_gemm1 only (stream-ordered safe).
  u16*  Wb16    = (u16*)(ws + 0x1730000);        // 512 KB f16 [8][64][64][8]

  k_wpack<<<dim3(128), dim3(256), 0, stream>>>(W, Wb16);
  k_gemm1<<<dim3(320, 8), dim3(256), 0, stream>>>(x, Wb16, av, adj, whB, bits_t, r1, e21h, e202h);
  k_att1<<<dim3(64, 8, 4), dim3(256), 0, stream>>>(whB, bits_t, r1, e21h, e202h, pnum1, pden1);
  k_gemm2<<<dim3(1024), dim3(256), 0, stream>>>(pnum1, pden1, Wout, aout, whoB, r1o, e21oh, e202oh);
  k_att2f<<<dim3(256), dim3(256), 0, stream>>>(whoB, bits_t, r1o, e21oh, e202oh, out);
}

// Round 9
// 178.619 us; speedup vs baseline: 1.0216x; 1.0216x over previous
//
#include <hip/hip_runtime.h>

// ---------------------------------------------------------------------------
// GAT (2-layer, dense mask) on gfx950 — R23.
// R22 post-mortem: +12us -> both changes reverted. Key R22 datum: gemm1 at
// Occ 30% is STILL 41.0us @ 1.26 TB/s; fill = 41us @ 6.45 TB/s;
// 1.26+6.45 ~ 7.7 ~ HBM peak => the harness poison fill runs concurrently
// and bandwidth-starves gemm1. gemm1 interior is unoptimizable (explains 5
// neutral rounds); it is fill-shadowed. Only confirmed-responsive lever:
// att1 barrier-drain count (KVBLK 64->128 = -4us).
// R23 = R20 exact + att1 KVBLK 128->256: 4 c-iters (4 drains/block, was 8),
// 2x MFMA per barrier, LDS 66KB -> 2 blocks/CU. Tests whether barrier-halving
// still beats occupancy-halving at 2 blocks/CU.
// ---------------------------------------------------------------------------

typedef _Float16 h2 __attribute__((ext_vector_type(2)));
typedef _Float16 half8 __attribute__((ext_vector_type(8)));
typedef __attribute__((ext_vector_type(4))) float f32x4;
typedef unsigned long long u64;
typedef unsigned short u16;
typedef unsigned int u32;

__device__ __forceinline__ u16 f2h(float f){
  union { _Float16 h; u16 u; } c; c.h = (_Float16)f; return c.u;
}
__device__ __forceinline__ h2 u2h2(u32 u){ union { u32 u; h2 h; } c; c.u = u; return c.h; }
__device__ __forceinline__ u32 h22u(h2 h){ union { u32 u; h2 h; } c; c.h = h; return c.u; }
__device__ __forceinline__ half8 pk2h8(uint4 v){ union { uint4 u; half8 h; } c; c.u = v; return c.h; }

__device__ __forceinline__ void async16(void* lds, const void* g){
  __builtin_amdgcn_global_load_lds((const __attribute__((address_space(1))) u32*)g,
                                   (__attribute__((address_space(3))) u32*)lds, 16, 0, 0);
}
__device__ __forceinline__ void async4(void* lds, const void* g){
  __builtin_amdgcn_global_load_lds((const __attribute__((address_space(1))) u32*)g,
                                   (__attribute__((address_space(3))) u32*)lds, 4, 0, 0);
}

// ===== K0: pack W f32 -> f16 B-layout [h][fgb(64)][o(64)][q(8)] ============
__global__ __launch_bounds__(256) void k_wpack(const float* __restrict__ W,
                                               u16* __restrict__ Wb16){
  int t = blockIdx.x * 256 + threadIdx.x;   // 0..32767 = 8 h x 64 fgb x 64 o
  int o   = t & 63;
  int fgb = (t >> 6) & 63;
  int h   = t >> 12;
  const float* src = W + ((size_t)h * 512 + fgb * 8) * 64 + o;
  u32 pk[4];
  #pragma unroll
  for (int p = 0; p < 4; ++p)
    pk[p] = (u32)f2h(src[(2 * p) * 64]) | ((u32)f2h(src[(2 * p + 1) * 64]) << 16);
  *(uint4*)(Wb16 + ((size_t)h * 4096 + fgb * 64 + o) * 8) = *(uint4*)pk;
}

// ===== K1: Wh = x @ W[h] (B-frags from global Wb16) + tables + whB,        =
// =====     plus block-specialized adj bitmask pack (bx >= 64)              =
__global__ __launch_bounds__(256) void k_gemm1(const float* __restrict__ x,
                                               const u16* __restrict__ Wb16,
                                               const float* __restrict__ av,
                                               const int* __restrict__ adj,
                                               u16* __restrict__ whB,
                                               u64* __restrict__ bits_t,
                                               float* __restrict__ r1,
                                               u16* __restrict__ e21h, u16* __restrict__ e202h){
  __shared__ u16 tr[4096];                 // 8 KB transpose buffer (only LDS)
  int h    = blockIdx.y;
  int bx   = blockIdx.x;
  int tid  = threadIdx.x;
  int lane = tid & 63;
  int wv   = tid >> 6;

  if (bx >= 64){
    // ---- adj-pack slice (transposed bitmask; independent of gemm) ----
    int B = h * 64 + (bx - 64);            // 0..511
    int uid0 = B * 512 + wv * 128;
    for (int k = 0; k < 128; k += 8){
      int v[8];
      #pragma unroll
      for (int q = 0; q < 8; ++q){
        int uid = uid0 + k + q;
        v[q] = adj[(size_t)(uid >> 6) * 4096 + ((uid & 63) << 6) + lane];
      }
      u64 m[8];
      #pragma unroll
      for (int q = 0; q < 8; ++q) m[q] = __ballot(v[q] != 0);
      if (lane == 0){
        #pragma unroll
        for (int q = 0; q < 8; ++q){
          int uid = uid0 + k + q;
          bits_t[(size_t)(uid & 63) * 4096 + (uid >> 6)] = m[q];
        }
      }
    }
    return;
  }

  // ---- gemm path ----
  int row16 = lane & 15, grp = lane >> 4;
  int n0 = bx * 64;
  int n0w = n0 + wv * 16;
  const u16* wb = Wb16 + (size_t)h * 32768;

  f32x4 acc[4] = {};
  #pragma unroll 4
  for (int ks = 0; ks < 16; ++ks){
    int fgb = ks * 4 + grp;
    const float* xs = x + (size_t)(n0w + row16) * 512 + fgb * 8;
    float4 xv0 = ((const float4*)xs)[0];
    float4 xv1 = ((const float4*)xs)[1];
    u32 ax[4];
    ax[0] = (u32)f2h(xv0.x) | ((u32)f2h(xv0.y) << 16);
    ax[1] = (u32)f2h(xv0.z) | ((u32)f2h(xv0.w) << 16);
    ax[2] = (u32)f2h(xv1.x) | ((u32)f2h(xv1.y) << 16);
    ax[3] = (u32)f2h(xv1.z) | ((u32)f2h(xv1.w) << 16);
    half8 af = pk2h8(*(uint4*)ax);
    #pragma unroll
    for (int nt = 0; nt < 4; ++nt){
      half8 bf = *(const half8*)(wb + ((size_t)fgb * 64 + nt * 16 + row16) * 8);
      acc[nt] = __builtin_amdgcn_mfma_f32_16x16x32_f16(af, bf, acc[nt], 0, 0, 0);
    }
  }
  // ---- scale-free score tables ----
  float a1v[4], a2v[4];
  #pragma unroll
  for (int nt = 0; nt < 4; ++nt){
    a1v[nt] = av[h * 128 + nt * 16 + row16];
    a2v[nt] = av[h * 128 + 64 + nt * 16 + row16];
  }
  #pragma unroll
  for (int r = 0; r < 4; ++r){
    float p1 = acc[0][r]*a1v[0] + acc[1][r]*a1v[1] + acc[2][r]*a1v[2] + acc[3][r]*a1v[3];
    float p2 = acc[0][r]*a2v[0] + acc[1][r]*a2v[1] + acc[2][r]*a2v[2] + acc[3][r]*a2v[3];
    #pragma unroll
    for (int d = 1; d < 16; d <<= 1){ p1 += __shfl_xor(p1, d, 64); p2 += __shfl_xor(p2, d, 64); }
    if (row16 == 0){
      int idx = h * 4096 + n0w + grp * 4 + r;
      r1[idx]    = __expf(-0.8f * p1);     // row scale e^{-0.8 s1}
      e21h[idx]  = f2h(__expf(p2));
      e202h[idx] = f2h(__expf(0.2f * p2));
    }
  }
  // ---- whB f16 pack via LDS transpose ----
  #pragma unroll
  for (int nt = 0; nt < 4; ++nt)
    #pragma unroll
    for (int r = 0; r < 4; ++r){
      int jl = wv * 16 + grp * 4 + r;
      int o  = nt * 16 + row16;
      tr[((jl >> 3) * 64 + o) * 8 + (jl & 7)] = f2h(acc[nt][r]);
    }
  __syncthreads();
  u16* dst = whB + (size_t)h * 262144 + (size_t)n0 * 64;
  #pragma unroll
  for (int q = 0; q < 2; ++q)
    *(uint4*)(dst + (tid * 2 + q) * 8) = *(const uint4*)(tr + (tid * 2 + q) * 8);
}

// ===== K2: layer-1 attention (LDS dbuf, KVBLK=256, f16 packed w-gen) =======
__global__ __launch_bounds__(256) void k_att1(const u16* __restrict__ whB,
                                              const u64* __restrict__ bits_t,
                                              const float* __restrict__ r1,
                                              const u16* __restrict__ e21h, const u16* __restrict__ e202h,
                                              u16* __restrict__ pnum, float* __restrict__ pden){
  __shared__ u16  smB[2][16384];           // 256 j x 64 o f16, [j/8][o][j&7] (64 KB)
  __shared__ u32  smT[2][2][128];          // staged f16 tables (512 B each)
  __shared__ u32  smLut[4];
  int h     = blockIdx.y;
  int iblk  = blockIdx.x;
  int split = blockIdx.z;
  int lane = threadIdx.x & 63;
  int wv   = threadIdx.x >> 6;
  int tid  = threadIdx.x;
  int row16 = lane & 15, grp = lane >> 4;
  if (threadIdx.x < 4)
    smLut[threadIdx.x] = ((threadIdx.x & 1) ? 0xFFFFu : 0u) | ((threadIdx.x & 2) ? 0xFFFF0000u : 0u);
  int i = iblk * 64 + wv * 16 + row16;
  int hoff = h * 4096;
  u32 rb = (u32)f2h(r1[hoff + i]); rb |= rb << 16;
  h2 rr = u2h2(rb);
  const u16* whBh = whB + (size_t)h * 262144;
  int jbeg = split * 1024;

  half8 bden;                              // ones-column B frag for den
  {
    u32 z[4] = {0,0,0,0};
    if (row16 == 0){ z[0]=0x3C003C00u; z[1]=0x3C003C00u; z[2]=0x3C003C00u; z[3]=0x3C003C00u; }
    bden = pk2h8(*(uint4*)z);
  }

  auto stage = [&](int bb, int j0){
    // 32 KB B-tile: 8 x async16 per thread, fully contiguous
    const char* g = (const char*)whBh + (size_t)j0 * 128 + tid * 16;
    char* l = (char*)(&smB[bb][0]) + tid * 16;
    #pragma unroll
    for (int k = 0; k < 8; ++k)
      async16(l + k * 4096, g + k * 4096);
    // 512 B per table = 256 f16 (exactly one KVBLK), two async4 rounds
    if (wv == 0){
      async4((char*)&smT[bb][0][0]       , (const char*)(e21h  + hoff + j0) + lane * 4);
      async4((char*)&smT[bb][0][0] + 256 , (const char*)(e21h  + hoff + j0) + 256 + lane * 4);
    } else if (wv == 1){
      async4((char*)&smT[bb][1][0]       , (const char*)(e202h + hoff + j0) + lane * 4);
      async4((char*)&smT[bb][1][0] + 256 , (const char*)(e202h + hoff + j0) + 256 + lane * 4);
    }
  };

  f32x4 acc[4] = {};
  f32x4 accden = {};
  stage(0, jbeg);
  for (int c = 0; c < 4; ++c){
    int bb = c & 1;
    u64 mrow[4];
    #pragma unroll
    for (int m = 0; m < 4; ++m)
      mrow[m] = bits_t[(size_t)(split * 16 + c * 4 + m) * 4096 + i];   // coalesced
    __syncthreads();                       // buf bb staged; buf bb^1 free
    if (c < 3) stage(bb ^ 1, jbeg + (c + 1) * 256);
    #pragma unroll
    for (int ks = 0; ks < 8; ++ks){
      uint4 e1q = *(const uint4*)((const char*)&smT[bb][0][0] + ks * 64 + grp * 16);
      uint4 e2q = *(const uint4*)((const char*)&smT[bb][1][0] + ks * 64 + grp * 16);
      u32 es[4] = {e1q.x, e1q.y, e1q.z, e1q.w};
      u32 gs[4] = {e2q.x, e2q.y, e2q.z, e2q.w};
      const u16* bbase = &smB[bb][(ks * 4 + grp) * 512];
      half8 bf0 = *(const half8*)(bbase + (0 * 16 + row16) * 8);
      half8 bf1 = *(const half8*)(bbase + (1 * 16 + row16) * 8);
      half8 bf2 = *(const half8*)(bbase + (2 * 16 + row16) * 8);
      half8 bf3 = *(const half8*)(bbase + (3 * 16 + row16) * 8);
      u32 mb = ((u32)(mrow[ks >> 1] >> ((ks & 1) * 32)) >> (grp * 8)) & 0xffu;
      u32 pk[4];
      #pragma unroll
      for (int t2i = 0; t2i < 4; ++t2i){
        h2 w = __builtin_elementwise_max(u2h2(es[t2i]), rr * u2h2(gs[t2i]));
        pk[t2i] = h22u(w) & smLut[(mb >> (2 * t2i)) & 3u];
      }
      half8 af = pk2h8(*(uint4*)pk);
      acc[0] = __builtin_amdgcn_mfma_f32_16x16x32_f16(af, bf0, acc[0], 0, 0, 0);
      acc[1] = __builtin_amdgcn_mfma_f32_16x16x32_f16(af, bf1, acc[1], 0, 0, 0);
      acc[2] = __builtin_amdgcn_mfma_f32_16x16x32_f16(af, bf2, acc[2], 0, 0, 0);
      acc[3] = __builtin_amdgcn_mfma_f32_16x16x32_f16(af, bf3, acc[3], 0, 0, 0);
      accden = __builtin_amdgcn_mfma_f32_16x16x32_f16(af, bden, accden, 0, 0, 0);
    }
  }

  #pragma unroll
  for (int r4 = 0; r4 < 4; ++r4){
    int n = iblk * 64 + wv * 16 + grp * 4 + r4;
    if (row16 == 0)
      pden[((size_t)split * 8 + h) * 4096 + n] = accden[r4];
    u16* dst = pnum + ((size_t)split * 4096 + n) * 512 + h * 64 + row16;
    #pragma unroll
    for (int nt = 0; nt < 4; ++nt)
      dst[nt * 16] = f2h(acc[nt][r4]);
  }
}

// ===== K3: combine + Who = h @ Wout + layer-2 tables (4 rows/block) ========
__global__ __launch_bounds__(256) void k_gemm2(const u16* __restrict__ pnum,
                                               const float* __restrict__ pden,
                                               const float* __restrict__ Wout,
                                               const float* __restrict__ aout,
                                               u16* __restrict__ whoB,
                                               float* __restrict__ r1o,
                                               u16* __restrict__ e21oh, u16* __restrict__ e202oh){
  __shared__ float hrowf[4][512];             // 8 KB combined+elu rows (f32)
  int n0  = blockIdx.x * 4;
  int tid = threadIdx.x;
  // ---- phase A: combine 4 splits + ELU, 64 threads per row ----
  {
    int nn = tid >> 6;                        // row 0..3
    int fc = tid & 63;                        // f-chunk 0..63
    int f0 = fc * 8;
    int hh = fc >> 3;                         // head = f0/64
    int n  = n0 + nn;
    float v[8] = {0.f,0.f,0.f,0.f,0.f,0.f,0.f,0.f};
    float d = 0.f;
    #pragma unroll
    for (int s = 0; s < 4; ++s){
      uint4 raw = *(const uint4*)(pnum + ((size_t)s * 4096 + n) * 512 + f0);
      u32 rw[4] = {raw.x, raw.y, raw.z, raw.w};
      #pragma unroll
      for (int q = 0; q < 4; ++q){
        h2 dh = u2h2(rw[q]);
        v[q * 2]     += (float)dh.x;
        v[q * 2 + 1] += (float)dh.y;
      }
      d += pden[((size_t)s * 8 + hh) * 4096 + n];
    }
    float dinv = 1.f / d;
    #pragma unroll
    for (int k = 0; k < 8; ++k){
      float val = v[k] * dinv;
      hrowf[nn][f0 + k] = val > 0.f ? val : (__expf(val) - 1.f);
    }
  }
  __syncthreads();
  // ---- phase B: who[n][c] via K-split dot (Wout stays in L1: 32 KB) ----
  int rl = tid >> 6;                          // row 0..3
  int kq = (tid >> 4) & 3;                    // K-quarter 0..3
  int c  = tid & 15;                          // out col 0..15
  int n  = n0 + rl;
  const float* hr = &hrowf[rl][kq * 128];
  const float* wp = Wout + (size_t)(kq * 128) * 16 + c;
  float a0 = 0.f, a1 = 0.f;
  #pragma unroll 16
  for (int f = 0; f < 128; f += 2){
    a0 += hr[f]     * wp[f * 16];
    a1 += hr[f + 1] * wp[f * 16 + 16];
  }
  float acc = a0 + a1;
  acc += __shfl_xor(acc, 16, 64);             // reduce over kq
  acc += __shfl_xor(acc, 32, 64);
  int lane = tid & 63;
  if ((lane >> 4) == 0)
    whoB[((size_t)(n >> 3) * 16 + c) * 8 + (n & 7)] = f2h(acc);
  float p1 = acc * aout[c], p2 = acc * aout[16 + c];
  #pragma unroll
  for (int d = 1; d < 16; d <<= 1){ p1 += __shfl_xor(p1, d, 64); p2 += __shfl_xor(p2, d, 64); }
  if (lane == 0){
    r1o[n]    = __expf(-0.8f * p1);
    e21oh[n]  = f2h(__expf(p2));
    e202oh[n] = f2h(__expf(0.2f * p2));
  }
}

// ===== K4: layer-2 attention (16-way split, f16, global-direct) ============
__global__ __launch_bounds__(256) void k_att2(const u16* __restrict__ whoB,
                                              const u64* __restrict__ bits_t,
                                              const float* __restrict__ r1o,
                                              const u16* __restrict__ e21oh, const u16* __restrict__ e202oh,
                                              float* __restrict__ pnum, float* __restrict__ pden){
  __shared__ u32 smLut[4];
  int iblk  = blockIdx.x;
  int split = blockIdx.y;                     // 0..15
  int lane = threadIdx.x & 63;
  int wv   = threadIdx.x >> 6;
  int row16 = lane & 15, grp = lane >> 4;
  if (threadIdx.x < 4)
    smLut[threadIdx.x] = ((threadIdx.x & 1) ? 0xFFFFu : 0u) | ((threadIdx.x & 2) ? 0xFFFF0000u : 0u);
  __syncthreads();
  int i = iblk * 64 + wv * 16 + row16;
  u32 rb = (u32)f2h(r1o[i]); rb |= rb << 16;
  h2 rr = u2h2(rb);
  int jbeg = split * 256;
  half8 bden;
  {
    u32 z[4] = {0,0,0,0};
    if (row16 == 0){ z[0]=0x3C003C00u; z[1]=0x3C003C00u; z[2]=0x3C003C00u; z[3]=0x3C003C00u; }
    bden = pk2h8(*(uint4*)z);
  }

  f32x4 acc = {};
  f32x4 accden = {};
  #pragma unroll
  for (int c = 0; c < 4; ++c){
    int j0 = jbeg + c * 64;
    u64 mrow = bits_t[(size_t)(split * 4 + c) * 4096 + i];   // coalesced
    #pragma unroll
    for (int ks = 0; ks < 2; ++ks){
      int sb = (j0 >> 3) + ks * 4 + grp;
      half8 bf = *(const half8*)(whoB + ((size_t)sb * 16 + row16) * 8);
      uint4 e1q = *(const uint4*)(e21oh  + j0 + ks * 32 + grp * 8);
      uint4 e2q = *(const uint4*)(e202oh + j0 + ks * 32 + grp * 8);
      u32 es[4] = {e1q.x, e1q.y, e1q.z, e1q.w};
      u32 gs[4] = {e2q.x, e2q.y, e2q.z, e2q.w};
      u32 mb = ((u32)(mrow >> (ks * 32)) >> (grp * 8)) & 0xffu;
      u32 pk[4];
      #pragma unroll
      for (int t2i = 0; t2i < 4; ++t2i){
        h2 w = __builtin_elementwise_max(u2h2(es[t2i]), rr * u2h2(gs[t2i]));
        pk[t2i] = h22u(w) & smLut[(mb >> (2 * t2i)) & 3u];
      }
      half8 af = pk2h8(*(uint4*)pk);
      acc    = __builtin_amdgcn_mfma_f32_16x16x32_f16(af, bf, acc, 0, 0, 0);
      accden = __builtin_amdgcn_mfma_f32_16x16x32_f16(af, bden, accden, 0, 0, 0);
    }
  }
  #pragma unroll
  for (int r4 = 0; r4 < 4; ++r4){
    int n = iblk * 64 + wv * 16 + grp * 4 + r4;
    if (row16 == 0)
      pden[(size_t)n * 16 + split] = accden[r4];
    pnum[((size_t)n * 16 + split) * 16 + row16] = acc[r4];
  }
}

// ===== K5: combine + elu + log_softmax =====================================
__global__ __launch_bounds__(256) void k_final(const float* __restrict__ pnum,
                                               const float* __restrict__ pden,
                                               float* __restrict__ out){
  int tid = blockIdx.x * 256 + threadIdx.x;   // 65536
  int c = tid & 15;
  int n = tid >> 4;
  float num = 0.f, den = 0.f;
  #pragma unroll
  for (int s = 0; s < 16; ++s){
    num += pnum[((size_t)n * 16 + s) * 16 + c];
    den += pden[(size_t)n * 16 + s];
  }
  float v = num / den;
  v = v > 0.f ? v : (__expf(v) - 1.f);
  float m = v;
  #pragma unroll
  for (int d = 1; d < 16; d <<= 1) m = fmaxf(m, __shfl_xor(m, d, 64));
  float es = __expf(v - m), ss = es;
  #pragma unroll
  for (int d = 1; d < 16; d <<= 1) ss += __shfl_xor(ss, d, 64);
  out[(size_t)n * 16 + c] = v - m - __logf(ss);
}

// ---------------------------------------------------------------------------
extern "C" void kernel_launch(void* const* d_in, const int* in_sizes, int n_in,
                              void* d_out, int out_size, void* d_ws, size_t ws_size,
                              hipStream_t stream){
  (void)in_sizes; (void)n_in; (void)out_size; (void)ws_size;
  const float* x    = (const float*)d_in[0];
  const int*   adj  = (const int*)d_in[1];
  const float* W    = (const float*)d_in[2];
  const float* av   = (const float*)d_in[3];
  const float* Wout = (const float*)d_in[4];
  const float* aout = (const float*)d_in[5];
  float* out = (float*)d_out;
  char* ws = (char*)d_ws;

  u64*  bits_t  = (u64*)(ws + 0x0000000);        // 2 MB [64][4096]
  u16*  whB     = (u16*)(ws + 0x0200000);        // 4 MB f16 [8][j/8][o][8]
  float* r1     = (float*)(ws + 0x0600000);      // 128 KB
  u16*  e21h    = (u16*)(ws + 0x0620000);        // 64 KB f16
  u16*  e202h   = (u16*)(ws + 0x0630000);        // 64 KB f16
  u16*  pnum1   = (u16*)(ws + 0x0680000);        // 16 MB f16 [4][4096][512]
  float* pden1  = (float*)(ws + 0x1680000);      // 512 KB [4][8][4096]
  u16*  whoB    = (u16*)(ws + 0x1700000);        // 128 KB f16
  float* r1o    = (float*)(ws + 0x1720000);      // 16 KB
  u16*  e21oh   = (u16*)(ws + 0x1724000);        // 8 KB f16
  u16*  e202oh  = (u16*)(ws + 0x1726000);        // 8 KB f16
  float* pnum2  = (float*)(ws + 0x1730000);      // 4 MB [4096][16][16]
  float* pden2  = (float*)(ws + 0x1B30000);      // 256 KB
  // Wb16 aliases pnum2's region: written by k_wpack, consumed by k_gemm1,
  // then dead before k_att2 overwrites the region (stream-ordered safe).
  u16*  Wb16    = (u16*)(ws + 0x1730000);        // 512 KB f16 [8][64][64][8]

  k_wpack<<<dim3(128), dim3(256), 0, stream>>>(W, Wb16);
  k_gemm1<<<dim3(128, 8), dim3(256), 0, stream>>>(x, Wb16, av, adj, whB, bits_t, r1, e21h, e202h);
  k_att1<<<dim3(64, 8, 4), dim3(256), 0, stream>>>(whB, bits_t, r1, e21h, e202h, pnum1, pden1);
  k_gemm2<<<dim3(1024), dim3(256), 0, stream>>>(pnum1, pden1, Wout, aout, whoB, r1o, e21oh, e202oh);
  k_att2<<<dim3(64, 16), dim3(256), 0, stream>>>(whoB, bits_t, r1o, e21oh, e202oh, pnum2, pden2);
  k_final<<<dim3(256), dim3(256), 0, stream>>>(pnum2, pden2, out);
}

// Round 11
// 174.234 us; speedup vs baseline: 1.0474x; 1.0252x over previous
//
#include <hip/hip_runtime.h>

// ---------------------------------------------------------------------------
// GAT (2-layer, dense mask) on gfx950 — R25 = R24 resubmit (container flake).
// R24 theory under test: att1 is barrier-drain limited at VGPR-capped 16
// waves/CU. Changes vs R20 (170.4us best):
//  (1) counted-vmcnt barrier (T4): issue next-tile stage BEFORE the barrier,
//      then s_waitcnt vmcnt(5) + s_barrier — the 5 prefetch loads stay in
//      flight across the barrier (old __syncthreads drained vmcnt(0)).
//      Uniform staging: every lane issues exactly 4 async16 + 1 async4.
//  (2) pnum epilogue via LDS transpose (aliased on dead smB[0], stride 72):
//      16 scattered 2B stores/thread -> 2 coalesced 16B stores/thread.
// Hang-safety audit: barriers uniform; vmcnt count conservative (compiler
// still inserts its own waits for value uses); trn alias ordered by the c=7
// barrier; duplicate table stages write identical bytes.
// ---------------------------------------------------------------------------

typedef _Float16 h2 __attribute__((ext_vector_type(2)));
typedef _Float16 half8 __attribute__((ext_vector_type(8)));
typedef __attribute__((ext_vector_type(4))) float f32x4;
typedef unsigned long long u64;
typedef unsigned short u16;
typedef unsigned int u32;

__device__ __forceinline__ u16 f2h(float f){
  union { _Float16 h; u16 u; } c; c.h = (_Float16)f; return c.u;
}
__device__ __forceinline__ h2 u2h2(u32 u){ union { u32 u; h2 h; } c; c.u = u; return c.h; }
__device__ __forceinline__ u32 h22u(h2 h){ union { u32 u; h2 h; } c; c.h = h; return c.u; }
__device__ __forceinline__ half8 pk2h8(uint4 v){ union { uint4 u; half8 h; } c; c.u = v; return c.h; }

__device__ __forceinline__ void async16(void* lds, const void* g){
  __builtin_amdgcn_global_load_lds((const __attribute__((address_space(1))) u32*)g,
                                   (__attribute__((address_space(3))) u32*)lds, 16, 0, 0);
}
__device__ __forceinline__ void async4(void* lds, const void* g){
  __builtin_amdgcn_global_load_lds((const __attribute__((address_space(1))) u32*)g,
                                   (__attribute__((address_space(3))) u32*)lds, 4, 0, 0);
}

// ===== K0: pack W f32 -> f16 B-layout [h][fgb(64)][o(64)][q(8)] ============
__global__ __launch_bounds__(256) void k_wpack(const float* __restrict__ W,
                                               u16* __restrict__ Wb16){
  int t = blockIdx.x * 256 + threadIdx.x;   // 0..32767 = 8 h x 64 fgb x 64 o
  int o   = t & 63;
  int fgb = (t >> 6) & 63;
  int h   = t >> 12;
  const float* src = W + ((size_t)h * 512 + fgb * 8) * 64 + o;
  u32 pk[4];
  #pragma unroll
  for (int p = 0; p < 4; ++p)
    pk[p] = (u32)f2h(src[(2 * p) * 64]) | ((u32)f2h(src[(2 * p + 1) * 64]) << 16);
  *(uint4*)(Wb16 + ((size_t)h * 4096 + fgb * 64 + o) * 8) = *(uint4*)pk;
}

// ===== K1: Wh = x @ W[h] (B-frags from global Wb16) + tables + whB,        =
// =====     plus block-specialized adj bitmask pack (bx >= 64)              =
__global__ __launch_bounds__(256) void k_gemm1(const float* __restrict__ x,
                                               const u16* __restrict__ Wb16,
                                               const float* __restrict__ av,
                                               const int* __restrict__ adj,
                                               u16* __restrict__ whB,
                                               u64* __restrict__ bits_t,
                                               float* __restrict__ r1,
                                               u16* __restrict__ e21h, u16* __restrict__ e202h){
  __shared__ u16 tr[4096];                 // 8 KB transpose buffer (only LDS)
  int h    = blockIdx.y;
  int bx   = blockIdx.x;
  int tid  = threadIdx.x;
  int lane = tid & 63;
  int wv   = tid >> 6;

  if (bx >= 64){
    // ---- adj-pack slice (transposed bitmask; independent of gemm) ----
    int B = h * 64 + (bx - 64);            // 0..511
    int uid0 = B * 512 + wv * 128;
    for (int k = 0; k < 128; k += 8){
      int v[8];
      #pragma unroll
      for (int q = 0; q < 8; ++q){
        int uid = uid0 + k + q;
        v[q] = adj[(size_t)(uid >> 6) * 4096 + ((uid & 63) << 6) + lane];
      }
      u64 m[8];
      #pragma unroll
      for (int q = 0; q < 8; ++q) m[q] = __ballot(v[q] != 0);
      if (lane == 0){
        #pragma unroll
        for (int q = 0; q < 8; ++q){
          int uid = uid0 + k + q;
          bits_t[(size_t)(uid & 63) * 4096 + (uid >> 6)] = m[q];
        }
      }
    }
    return;
  }

  // ---- gemm path ----
  int row16 = lane & 15, grp = lane >> 4;
  int n0 = bx * 64;
  int n0w = n0 + wv * 16;
  const u16* wb = Wb16 + (size_t)h * 32768;

  f32x4 acc[4] = {};
  #pragma unroll 4
  for (int ks = 0; ks < 16; ++ks){
    int fgb = ks * 4 + grp;
    const float* xs = x + (size_t)(n0w + row16) * 512 + fgb * 8;
    float4 xv0 = ((const float4*)xs)[0];
    float4 xv1 = ((const float4*)xs)[1];
    u32 ax[4];
    ax[0] = (u32)f2h(xv0.x) | ((u32)f2h(xv0.y) << 16);
    ax[1] = (u32)f2h(xv0.z) | ((u32)f2h(xv0.w) << 16);
    ax[2] = (u32)f2h(xv1.x) | ((u32)f2h(xv1.y) << 16);
    ax[3] = (u32)f2h(xv1.z) | ((u32)f2h(xv1.w) << 16);
    half8 af = pk2h8(*(uint4*)ax);
    #pragma unroll
    for (int nt = 0; nt < 4; ++nt){
      half8 bf = *(const half8*)(wb + ((size_t)fgb * 64 + nt * 16 + row16) * 8);
      acc[nt] = __builtin_amdgcn_mfma_f32_16x16x32_f16(af, bf, acc[nt], 0, 0, 0);
    }
  }
  // ---- scale-free score tables ----
  float a1v[4], a2v[4];
  #pragma unroll
  for (int nt = 0; nt < 4; ++nt){
    a1v[nt] = av[h * 128 + nt * 16 + row16];
    a2v[nt] = av[h * 128 + 64 + nt * 16 + row16];
  }
  #pragma unroll
  for (int r = 0; r < 4; ++r){
    float p1 = acc[0][r]*a1v[0] + acc[1][r]*a1v[1] + acc[2][r]*a1v[2] + acc[3][r]*a1v[3];
    float p2 = acc[0][r]*a2v[0] + acc[1][r]*a2v[1] + acc[2][r]*a2v[2] + acc[3][r]*a2v[3];
    #pragma unroll
    for (int d = 1; d < 16; d <<= 1){ p1 += __shfl_xor(p1, d, 64); p2 += __shfl_xor(p2, d, 64); }
    if (row16 == 0){
      int idx = h * 4096 + n0w + grp * 4 + r;
      r1[idx]    = __expf(-0.8f * p1);     // row scale e^{-0.8 s1}
      e21h[idx]  = f2h(__expf(p2));
      e202h[idx] = f2h(__expf(0.2f * p2));
    }
  }
  // ---- whB f16 pack via LDS transpose ----
  #pragma unroll
  for (int nt = 0; nt < 4; ++nt)
    #pragma unroll
    for (int r = 0; r < 4; ++r){
      int jl = wv * 16 + grp * 4 + r;
      int o  = nt * 16 + row16;
      tr[((jl >> 3) * 64 + o) * 8 + (jl & 7)] = f2h(acc[nt][r]);
    }
  __syncthreads();
  u16* dst = whB + (size_t)h * 262144 + (size_t)n0 * 64;
  #pragma unroll
  for (int q = 0; q < 2; ++q)
    *(uint4*)(dst + (tid * 2 + q) * 8) = *(const uint4*)(tr + (tid * 2 + q) * 8);
}

// ===== K2: layer-1 attention (KVBLK=128, counted-vmcnt dbuf) ===============
__global__ __launch_bounds__(256) void k_att1(const u16* __restrict__ whB,
                                              const u64* __restrict__ bits_t,
                                              const float* __restrict__ r1,
                                              const u16* __restrict__ e21h, const u16* __restrict__ e202h,
                                              u16* __restrict__ pnum, float* __restrict__ pden){
  __shared__ u16  smB[2][8192];            // 128 j x 64 o f16, [j/8][o][j&7]
  __shared__ u32  smT[2][2][64];           // staged f16 tables (256 B each)
  __shared__ u32  smLut[4];
  int h     = blockIdx.y;
  int iblk  = blockIdx.x;
  int split = blockIdx.z;
  int tid  = threadIdx.x;
  int lane = tid & 63;
  int wv   = tid >> 6;
  int row16 = lane & 15, grp = lane >> 4;
  if (tid < 4)
    smLut[tid] = ((tid & 1) ? 0xFFFFu : 0u) | ((tid & 2) ? 0xFFFF0000u : 0u);
  int i = iblk * 64 + wv * 16 + row16;
  int hoff = h * 4096;
  u32 rb = (u32)f2h(r1[hoff + i]); rb |= rb << 16;
  h2 rr = u2h2(rb);
  const u16* whBh = whB + (size_t)h * 262144;
  int jbeg = split * 1024;

  half8 bden;                              // ones-column B frag for den
  {
    u32 z[4] = {0,0,0,0};
    if (row16 == 0){ z[0]=0x3C003C00u; z[1]=0x3C003C00u; z[2]=0x3C003C00u; z[3]=0x3C003C00u; }
    bden = pk2h8(*(uint4*)z);
  }

  // uniform staging: every lane issues exactly 4 async16 + 1 async4 = 5
  // (waves 2/3 duplicate-stage the tables: same src -> same dst, benign)
  auto stage = [&](int bb, int j0){
    const char* g = (const char*)whBh + (size_t)j0 * 128 + tid * 16;
    char* l = (char*)(&smB[bb][0]) + tid * 16;
    #pragma unroll
    for (int k = 0; k < 4; ++k)
      async16(l + k * 4096, g + k * 4096);
    int tsel = wv & 1;
    const u16* tb = tsel ? e202h : e21h;
    async4(&smT[bb][tsel][0], (const char*)(tb + hoff + j0) + lane * 4);
  };

  f32x4 acc[4] = {};
  f32x4 accden = {};
  stage(0, jbeg);
  for (int c = 0; c < 8; ++c){
    int bb = c & 1;
    u64 mrow0 = bits_t[(size_t)(split * 16 + c * 2)     * 4096 + i];   // coalesced
    u64 mrow1 = bits_t[(size_t)(split * 16 + c * 2 + 1) * 4096 + i];
    if (c < 7){
      stage(bb ^ 1, jbeg + (c + 1) * 128);   // issue prefetch BEFORE barrier
      asm volatile("s_waitcnt vmcnt(5)" ::: "memory");  // keep 5 newest in flight
    } else {
      asm volatile("s_waitcnt vmcnt(0)" ::: "memory");
    }
    __builtin_amdgcn_s_barrier();            // all waves' stage(bb) landed
    #pragma unroll
    for (int ks = 0; ks < 4; ++ks){
      uint4 e1q = *(const uint4*)((const char*)&smT[bb][0][0] + ks * 64 + grp * 16);
      uint4 e2q = *(const uint4*)((const char*)&smT[bb][1][0] + ks * 64 + grp * 16);
      u32 es[4] = {e1q.x, e1q.y, e1q.z, e1q.w};
      u32 gs[4] = {e2q.x, e2q.y, e2q.z, e2q.w};
      const u16* bbase = &smB[bb][(ks * 4 + grp) * 512];
      half8 bf0 = *(const half8*)(bbase + (0 * 16 + row16) * 8);
      half8 bf1 = *(const half8*)(bbase + (1 * 16 + row16) * 8);
      half8 bf2 = *(const half8*)(bbase + (2 * 16 + row16) * 8);
      half8 bf3 = *(const half8*)(bbase + (3 * 16 + row16) * 8);
      u64 mrow = (ks < 2) ? mrow0 : mrow1;
      u32 mb = ((u32)(mrow >> ((ks & 1) * 32)) >> (grp * 8)) & 0xffu;
      u32 pk[4];
      #pragma unroll
      for (int t2i = 0; t2i < 4; ++t2i){
        h2 w = __builtin_elementwise_max(u2h2(es[t2i]), rr * u2h2(gs[t2i]));
        pk[t2i] = h22u(w) & smLut[(mb >> (2 * t2i)) & 3u];
      }
      half8 af = pk2h8(*(uint4*)pk);
      acc[0] = __builtin_amdgcn_mfma_f32_16x16x32_f16(af, bf0, acc[0], 0, 0, 0);
      acc[1] = __builtin_amdgcn_mfma_f32_16x16x32_f16(af, bf1, acc[1], 0, 0, 0);
      acc[2] = __builtin_amdgcn_mfma_f32_16x16x32_f16(af, bf2, acc[2], 0, 0, 0);
      acc[3] = __builtin_amdgcn_mfma_f32_16x16x32_f16(af, bf3, acc[3], 0, 0, 0);
      accden = __builtin_amdgcn_mfma_f32_16x16x32_f16(af, bden, accden, 0, 0, 0);
    }
  }

  // ---- epilogue: pden (tiny, unchanged) ----
  #pragma unroll
  for (int r4 = 0; r4 < 4; ++r4){
    int n = iblk * 64 + wv * 16 + grp * 4 + r4;
    if (row16 == 0)
      pden[((size_t)split * 8 + h) * 4096 + n] = accden[r4];
  }
  // ---- pnum via LDS transpose: 16x2B scattered -> 2x16B coalesced ----
  // trn aliases smB[0] (last read at c=6; all waves past the c=7 barrier).
  u16* trn = (u16*)&smB[0][0];              // [64][72] u16, 9216 B
  #pragma unroll
  for (int nt = 0; nt < 4; ++nt)
    #pragma unroll
    for (int r4 = 0; r4 < 4; ++r4){
      int nl = wv * 16 + grp * 4 + r4;
      trn[nl * 72 + nt * 16 + row16] = f2h(acc[nt][r4]);
    }
  __syncthreads();
  {
    int rl = tid >> 2;                      // row 0..63
    int q  = tid & 3;                       // 32B chunk 0..3
    int n  = iblk * 64 + rl;
    const uint4* src = (const uint4*)(trn + rl * 72 + q * 16);
    u16* dst = pnum + ((size_t)split * 4096 + n) * 512 + h * 64 + q * 16;
    ((uint4*)dst)[0] = src[0];
    ((uint4*)dst)[1] = src[1];
  }
}

// ===== K3: combine + Who = h @ Wout + layer-2 tables (4 rows/block) ========
__global__ __launch_bounds__(256) void k_gemm2(const u16* __restrict__ pnum,
                                               const float* __restrict__ pden,
                                               const float* __restrict__ Wout,
                                               const float* __restrict__ aout,
                                               u16* __restrict__ whoB,
                                               float* __restrict__ r1o,
                                               u16* __restrict__ e21oh, u16* __restrict__ e202oh){
  __shared__ float hrowf[4][512];             // 8 KB combined+elu rows (f32)
  int n0  = blockIdx.x * 4;
  int tid = threadIdx.x;
  // ---- phase A: combine 4 splits + ELU, 64 threads per row ----
  {
    int nn = tid >> 6;                        // row 0..3
    int fc = tid & 63;                        // f-chunk 0..63
    int f0 = fc * 8;
    int hh = fc >> 3;                         // head = f0/64
    int n  = n0 + nn;
    float v[8] = {0.f,0.f,0.f,0.f,0.f,0.f,0.f,0.f};
    float d = 0.f;
    #pragma unroll
    for (int s = 0; s < 4; ++s){
      uint4 raw = *(const uint4*)(pnum + ((size_t)s * 4096 + n) * 512 + f0);
      u32 rw[4] = {raw.x, raw.y, raw.z, raw.w};
      #pragma unroll
      for (int q = 0; q < 4; ++q){
        h2 dh = u2h2(rw[q]);
        v[q * 2]     += (float)dh.x;
        v[q * 2 + 1] += (float)dh.y;
      }
      d += pden[((size_t)s * 8 + hh) * 4096 + n];
    }
    float dinv = 1.f / d;
    #pragma unroll
    for (int k = 0; k < 8; ++k){
      float val = v[k] * dinv;
      hrowf[nn][f0 + k] = val > 0.f ? val : (__expf(val) - 1.f);
    }
  }
  __syncthreads();
  // ---- phase B: who[n][c] via K-split dot (Wout stays in L1: 32 KB) ----
  int rl = tid >> 6;                          // row 0..3
  int kq = (tid >> 4) & 3;                    // K-quarter 0..3
  int c  = tid & 15;                          // out col 0..15
  int n  = n0 + rl;
  const float* hr = &hrowf[rl][kq * 128];
  const float* wp = Wout + (size_t)(kq * 128) * 16 + c;
  float a0 = 0.f, a1 = 0.f;
  #pragma unroll 16
  for (int f = 0; f < 128; f += 2){
    a0 += hr[f]     * wp[f * 16];
    a1 += hr[f + 1] * wp[f * 16 + 16];
  }
  float acc = a0 + a1;
  acc += __shfl_xor(acc, 16, 64);             // reduce over kq
  acc += __shfl_xor(acc, 32, 64);
  int lane = tid & 63;
  if ((lane >> 4) == 0)
    whoB[((size_t)(n >> 3) * 16 + c) * 8 + (n & 7)] = f2h(acc);
  float p1 = acc * aout[c], p2 = acc * aout[16 + c];
  #pragma unroll
  for (int d = 1; d < 16; d <<= 1){ p1 += __shfl_xor(p1, d, 64); p2 += __shfl_xor(p2, d, 64); }
  if (lane == 0){
    r1o[n]    = __expf(-0.8f * p1);
    e21oh[n]  = f2h(__expf(p2));
    e202oh[n] = f2h(__expf(0.2f * p2));
  }
}

// ===== K4: layer-2 attention (16-way split, f16, global-direct) ============
__global__ __launch_bounds__(256) void k_att2(const u16* __restrict__ whoB,
                                              const u64* __restrict__ bits_t,
                                              const float* __restrict__ r1o,
                                              const u16* __restrict__ e21oh, const u16* __restrict__ e202oh,
                                              float* __restrict__ pnum, float* __restrict__ pden){
  __shared__ u32 smLut[4];
  int iblk  = blockIdx.x;
  int split = blockIdx.y;                     // 0..15
  int lane = threadIdx.x & 63;
  int wv   = threadIdx.x >> 6;
  int row16 = lane & 15, grp = lane >> 4;
  if (threadIdx.x < 4)
    smLut[threadIdx.x] = ((threadIdx.x & 1) ? 0xFFFFu : 0u) | ((threadIdx.x & 2) ? 0xFFFF0000u : 0u);
  __syncthreads();
  int i = iblk * 64 + wv * 16 + row16;
  u32 rb = (u32)f2h(r1o[i]); rb |= rb << 16;
  h2 rr = u2h2(rb);
  int jbeg = split * 256;
  half8 bden;
  {
    u32 z[4] = {0,0,0,0};
    if (row16 == 0){ z[0]=0x3C003C00u; z[1]=0x3C003C00u; z[2]=0x3C003C00u; z[3]=0x3C003C00u; }
    bden = pk2h8(*(uint4*)z);
  }

  f32x4 acc = {};
  f32x4 accden = {};
  #pragma unroll
  for (int c = 0; c < 4; ++c){
    int j0 = jbeg + c * 64;
    u64 mrow = bits_t[(size_t)(split * 4 + c) * 4096 + i];   // coalesced
    #pragma unroll
    for (int ks = 0; ks < 2; ++ks){
      int sb = (j0 >> 3) + ks * 4 + grp;
      half8 bf = *(const half8*)(whoB + ((size_t)sb * 16 + row16) * 8);
      uint4 e1q = *(const uint4*)(e21oh  + j0 + ks * 32 + grp * 8);
      uint4 e2q = *(const uint4*)(e202oh + j0 + ks * 32 + grp * 8);
      u32 es[4] = {e1q.x, e1q.y, e1q.z, e1q.w};
      u32 gs[4] = {e2q.x, e2q.y, e2q.z, e2q.w};
      u32 mb = ((u32)(mrow >> (ks * 32)) >> (grp * 8)) & 0xffu;
      u32 pk[4];
      #pragma unroll
      for (int t2i = 0; t2i < 4; ++t2i){
        h2 w = __builtin_elementwise_max(u2h2(es[t2i]), rr * u2h2(gs[t2i]));
        pk[t2i] = h22u(w) & smLut[(mb >> (2 * t2i)) & 3u];
      }
      half8 af = pk2h8(*(uint4*)pk);
      acc    = __builtin_amdgcn_mfma_f32_16x16x32_f16(af, bf, acc, 0, 0, 0);
      accden = __builtin_amdgcn_mfma_f32_16x16x32_f16(af, bden, accden, 0, 0, 0);
    }
  }
  #pragma unroll
  for (int r4 = 0; r4 < 4; ++r4){
    int n = iblk * 64 + wv * 16 + grp * 4 + r4;
    if (row16 == 0)
      pden[(size_t)n * 16 + split] = accden[r4];
    pnum[((size_t)n * 16 + split) * 16 + row16] = acc[r4];
  }
}

// ===== K5: combine + elu + log_softmax =====================================
__global__ __launch_bounds__(256) void k_final(const float* __restrict__ pnum,
                                               const float* __restrict__ pden,
                                               float* __restrict__ out){
  int tid = blockIdx.x * 256 + threadIdx.x;   // 65536
  int c = tid & 15;
  int n = tid >> 4;
  float num = 0.f, den = 0.f;
  #pragma unroll
  for (int s = 0; s < 16; ++s){
    num += pnum[((size_t)n * 16 + s) * 16 + c];
    den += pden[(size_t)n * 16 + s];
  }
  float v = num / den;
  v = v > 0.f ? v : (__expf(v) - 1.f);
  float m = v;
  #pragma unroll
  for (int d = 1; d < 16; d <<= 1) m = fmaxf(m, __shfl_xor(m, d, 64));
  float es = __expf(v - m), ss = es;
  #pragma unroll
  for (int d = 1; d < 16; d <<= 1) ss += __shfl_xor(ss, d, 64);
  out[(size_t)n * 16 + c] = v - m - __logf(ss);
}

// ---------------------------------------------------------------------------
extern "C" void kernel_launch(void* const* d_in, const int* in_sizes, int n_in,
                              void* d_out, int out_size, void* d_ws, size_t ws_size,
                              hipStream_t stream){
  (void)in_sizes; (void)n_in; (void)out_size; (void)ws_size;
  const float* x    = (const float*)d_in[0];
  const int*   adj  = (const int*)d_in[1];
  const float* W    = (const float*)d_in[2];
  const float* av   = (const float*)d_in[3];
  const float* Wout = (const float*)d_in[4];
  const float* aout = (const float*)d_in[5];
  float* out = (float*)d_out;
  char* ws = (char*)d_ws;

  u64*  bits_t  = (u64*)(ws + 0x0000000);        // 2 MB [64][4096]
  u16*  whB     = (u16*)(ws + 0x0200000);        // 4 MB f16 [8][j/8][o][8]
  float* r1     = (float*)(ws + 0x0600000);      // 128 KB
  u16*  e21h    = (u16*)(ws + 0x0620000);        // 64 KB f16
  u16*  e202h   = (u16*)(ws + 0x0630000);        // 64 KB f16
  u16*  pnum1   = (u16*)(ws + 0x0680000);        // 16 MB f16 [4][4096][512]
  float* pden1  = (float*)(ws + 0x1680000);      // 512 KB [4][8][4096]
  u16*  whoB    = (u16*)(ws + 0x1700000);        // 128 KB f16
  float* r1o    = (float*)(ws + 0x1720000);      // 16 KB
  u16*  e21oh   = (u16*)(ws + 0x1724000);        // 8 KB f16
  u16*  e202oh  = (u16*)(ws + 0x1726000);        // 8 KB f16
  float* pnum2  = (float*)(ws + 0x1730000);      // 4 MB [4096][16][16]
  float* pden2  = (float*)(ws + 0x1B30000);      // 256 KB
  // Wb16 aliases pnum2's region: written by k_wpack, consumed by k_gemm1,
  // then dead before k_att2 overwrites the region (stream-ordered safe).
  u16*  Wb16    = (u16*)(ws + 0x1730000);        // 512 KB f16 [8][64][64][8]

  k_wpack<<<dim3(128), dim3(256), 0, stream>>>(W, Wb16);
  k_gemm1<<<dim3(128, 8), dim3(256), 0, stream>>>(x, Wb16, av, adj, whB, bits_t, r1, e21h, e202h);
  k_att1<<<dim3(64, 8, 4), dim3(256), 0, stream>>>(whB, bits_t, r1, e21h, e202h, pnum1, pden1);
  k_gemm2<<<dim3(1024), dim3(256), 0, stream>>>(pnum1, pden1, Wout, aout, whoB, r1o, e21oh, e202oh);
  k_att2<<<dim3(64, 16), dim3(256), 0, stream>>>(whoB, bits_t, r1o, e21oh, e202oh, pnum2, pden2);
  k_final<<<dim3(256), dim3(256), 0, stream>>>(pnum2, pden2, out);
}

// Round 12
// 169.898 us; speedup vs baseline: 1.0741x; 1.0255x over previous
//
#include <hip/hip_runtime.h>

// ---------------------------------------------------------------------------
// GAT (2-layer, dense mask) on gfx950 — R26 = exact revert to R20 (session
// best, 170.4 us). Final configuration after 11 polish experiments:
//  - k_wpack: W f32->f16 B-frag pack once (512 KB, L2-hot).
//  - k_gemm1: gemm blocks read Wb16 global-direct (8 KB LDS only) in
//    parallel with adj-pack blocks. Interior is FILL-SHADOWED: the harness's
//    268 MB workspace poison fill runs concurrently at ~6.4 TB/s, starving
//    gemm1 to ~1.2 TB/s; 6 interior variants (R15/R18/R21/R22) all ~41-43us.
//  - k_att1: KVBLK=128 LDS double-buffer (33 KB, 4 blocks/CU; VGPR=88 caps
//    at 16 waves/CU). KVBLK 64->128 was -4us (barrier-drain halved); 256
//    regressed (occupancy); explicit vmcnt + coalesced stores neutral (R25).
//  - k_gemm2: 4 rows/block, 1024 blocks, 8 KB LDS, 1 barrier (R19).
//  - k_att2/k_final: global-direct f16 MFMA + combine/log-softmax; fusion
//    attempt regressed (R22, 1 block/CU latency-bound).
// ---------------------------------------------------------------------------

typedef _Float16 h2 __attribute__((ext_vector_type(2)));
typedef _Float16 half8 __attribute__((ext_vector_type(8)));
typedef __attribute__((ext_vector_type(4))) float f32x4;
typedef unsigned long long u64;
typedef unsigned short u16;
typedef unsigned int u32;

__device__ __forceinline__ u16 f2h(float f){
  union { _Float16 h; u16 u; } c; c.h = (_Float16)f; return c.u;
}
__device__ __forceinline__ h2 u2h2(u32 u){ union { u32 u; h2 h; } c; c.u = u; return c.h; }
__device__ __forceinline__ u32 h22u(h2 h){ union { u32 u; h2 h; } c; c.h = h; return c.u; }
__device__ __forceinline__ half8 pk2h8(uint4 v){ union { uint4 u; half8 h; } c; c.u = v; return c.h; }

__device__ __forceinline__ void async16(void* lds, const void* g){
  __builtin_amdgcn_global_load_lds((const __attribute__((address_space(1))) u32*)g,
                                   (__attribute__((address_space(3))) u32*)lds, 16, 0, 0);
}
__device__ __forceinline__ void async4(void* lds, const void* g){
  __builtin_amdgcn_global_load_lds((const __attribute__((address_space(1))) u32*)g,
                                   (__attribute__((address_space(3))) u32*)lds, 4, 0, 0);
}

// ===== K0: pack W f32 -> f16 B-layout [h][fgb(64)][o(64)][q(8)] ============
__global__ __launch_bounds__(256) void k_wpack(const float* __restrict__ W,
                                               u16* __restrict__ Wb16){
  int t = blockIdx.x * 256 + threadIdx.x;   // 0..32767 = 8 h x 64 fgb x 64 o
  int o   = t & 63;
  int fgb = (t >> 6) & 63;
  int h   = t >> 12;
  const float* src = W + ((size_t)h * 512 + fgb * 8) * 64 + o;
  u32 pk[4];
  #pragma unroll
  for (int p = 0; p < 4; ++p)
    pk[p] = (u32)f2h(src[(2 * p) * 64]) | ((u32)f2h(src[(2 * p + 1) * 64]) << 16);
  *(uint4*)(Wb16 + ((size_t)h * 4096 + fgb * 64 + o) * 8) = *(uint4*)pk;
}

// ===== K1: Wh = x @ W[h] (B-frags from global Wb16) + tables + whB,        =
// =====     plus block-specialized adj bitmask pack (bx >= 64)              =
__global__ __launch_bounds__(256) void k_gemm1(const float* __restrict__ x,
                                               const u16* __restrict__ Wb16,
                                               const float* __restrict__ av,
                                               const int* __restrict__ adj,
                                               u16* __restrict__ whB,
                                               u64* __restrict__ bits_t,
                                               float* __restrict__ r1,
                                               u16* __restrict__ e21h, u16* __restrict__ e202h){
  __shared__ u16 tr[4096];                 // 8 KB transpose buffer (only LDS)
  int h    = blockIdx.y;
  int bx   = blockIdx.x;
  int tid  = threadIdx.x;
  int lane = tid & 63;
  int wv   = tid >> 6;

  if (bx >= 64){
    // ---- adj-pack slice (transposed bitmask; independent of gemm) ----
    int B = h * 64 + (bx - 64);            // 0..511
    int uid0 = B * 512 + wv * 128;
    for (int k = 0; k < 128; k += 8){
      int v[8];
      #pragma unroll
      for (int q = 0; q < 8; ++q){
        int uid = uid0 + k + q;
        v[q] = adj[(size_t)(uid >> 6) * 4096 + ((uid & 63) << 6) + lane];
      }
      u64 m[8];
      #pragma unroll
      for (int q = 0; q < 8; ++q) m[q] = __ballot(v[q] != 0);
      if (lane == 0){
        #pragma unroll
        for (int q = 0; q < 8; ++q){
          int uid = uid0 + k + q;
          bits_t[(size_t)(uid & 63) * 4096 + (uid >> 6)] = m[q];
        }
      }
    }
    return;
  }

  // ---- gemm path ----
  int row16 = lane & 15, grp = lane >> 4;
  int n0 = bx * 64;
  int n0w = n0 + wv * 16;
  const u16* wb = Wb16 + (size_t)h * 32768;

  f32x4 acc[4] = {};
  #pragma unroll 4
  for (int ks = 0; ks < 16; ++ks){
    int fgb = ks * 4 + grp;
    const float* xs = x + (size_t)(n0w + row16) * 512 + fgb * 8;
    float4 xv0 = ((const float4*)xs)[0];
    float4 xv1 = ((const float4*)xs)[1];
    u32 ax[4];
    ax[0] = (u32)f2h(xv0.x) | ((u32)f2h(xv0.y) << 16);
    ax[1] = (u32)f2h(xv0.z) | ((u32)f2h(xv0.w) << 16);
    ax[2] = (u32)f2h(xv1.x) | ((u32)f2h(xv1.y) << 16);
    ax[3] = (u32)f2h(xv1.z) | ((u32)f2h(xv1.w) << 16);
    half8 af = pk2h8(*(uint4*)ax);
    #pragma unroll
    for (int nt = 0; nt < 4; ++nt){
      half8 bf = *(const half8*)(wb + ((size_t)fgb * 64 + nt * 16 + row16) * 8);
      acc[nt] = __builtin_amdgcn_mfma_f32_16x16x32_f16(af, bf, acc[nt], 0, 0, 0);
    }
  }
  // ---- scale-free score tables ----
  float a1v[4], a2v[4];
  #pragma unroll
  for (int nt = 0; nt < 4; ++nt){
    a1v[nt] = av[h * 128 + nt * 16 + row16];
    a2v[nt] = av[h * 128 + 64 + nt * 16 + row16];
  }
  #pragma unroll
  for (int r = 0; r < 4; ++r){
    float p1 = acc[0][r]*a1v[0] + acc[1][r]*a1v[1] + acc[2][r]*a1v[2] + acc[3][r]*a1v[3];
    float p2 = acc[0][r]*a2v[0] + acc[1][r]*a2v[1] + acc[2][r]*a2v[2] + acc[3][r]*a2v[3];
    #pragma unroll
    for (int d = 1; d < 16; d <<= 1){ p1 += __shfl_xor(p1, d, 64); p2 += __shfl_xor(p2, d, 64); }
    if (row16 == 0){
      int idx = h * 4096 + n0w + grp * 4 + r;
      r1[idx]    = __expf(-0.8f * p1);     // row scale e^{-0.8 s1}
      e21h[idx]  = f2h(__expf(p2));
      e202h[idx] = f2h(__expf(0.2f * p2));
    }
  }
  // ---- whB f16 pack via LDS transpose ----
  #pragma unroll
  for (int nt = 0; nt < 4; ++nt)
    #pragma unroll
    for (int r = 0; r < 4; ++r){
      int jl = wv * 16 + grp * 4 + r;
      int o  = nt * 16 + row16;
      tr[((jl >> 3) * 64 + o) * 8 + (jl & 7)] = f2h(acc[nt][r]);
    }
  __syncthreads();
  u16* dst = whB + (size_t)h * 262144 + (size_t)n0 * 64;
  #pragma unroll
  for (int q = 0; q < 2; ++q)
    *(uint4*)(dst + (tid * 2 + q) * 8) = *(const uint4*)(tr + (tid * 2 + q) * 8);
}

// ===== K2: layer-1 attention (LDS dbuf, KVBLK=128, f16 packed w-gen) =======
__global__ __launch_bounds__(256) void k_att1(const u16* __restrict__ whB,
                                              const u64* __restrict__ bits_t,
                                              const float* __restrict__ r1,
                                              const u16* __restrict__ e21h, const u16* __restrict__ e202h,
                                              u16* __restrict__ pnum, float* __restrict__ pden){
  __shared__ u16  smB[2][8192];            // 128 j x 64 o f16, [j/8][o][j&7]
  __shared__ u32  smT[2][2][64];           // staged f16 tables (256 B each)
  __shared__ u32  smLut[4];
  int h     = blockIdx.y;
  int iblk  = blockIdx.x;
  int split = blockIdx.z;
  int lane = threadIdx.x & 63;
  int wv   = threadIdx.x >> 6;
  int tid  = threadIdx.x;
  int row16 = lane & 15, grp = lane >> 4;
  if (threadIdx.x < 4)
    smLut[threadIdx.x] = ((threadIdx.x & 1) ? 0xFFFFu : 0u) | ((threadIdx.x & 2) ? 0xFFFF0000u : 0u);
  int i = iblk * 64 + wv * 16 + row16;
  int hoff = h * 4096;
  u32 rb = (u32)f2h(r1[hoff + i]); rb |= rb << 16;
  h2 rr = u2h2(rb);
  const u16* whBh = whB + (size_t)h * 262144;
  int jbeg = split * 1024;

  half8 bden;                              // ones-column B frag for den
  {
    u32 z[4] = {0,0,0,0};
    if (row16 == 0){ z[0]=0x3C003C00u; z[1]=0x3C003C00u; z[2]=0x3C003C00u; z[3]=0x3C003C00u; }
    bden = pk2h8(*(uint4*)z);
  }

  auto stage = [&](int bb, int j0){
    // 16 KB B-tile: 4 x async16 per thread, fully contiguous
    const char* g = (const char*)whBh + (size_t)j0 * 128 + tid * 16;
    char* l = (char*)(&smB[bb][0]) + tid * 16;
    #pragma unroll
    for (int k = 0; k < 4; ++k)
      async16(l + k * 4096, g + k * 4096);
    // 256 B per table = 128 f16 (exactly one KVBLK)
    if (wv == 0)      async4(&smT[bb][0][0], (const char*)(e21h  + hoff + j0) + lane * 4);
    else if (wv == 1) async4(&smT[bb][1][0], (const char*)(e202h + hoff + j0) + lane * 4);
  };

  f32x4 acc[4] = {};
  f32x4 accden = {};
  stage(0, jbeg);
  for (int c = 0; c < 8; ++c){
    int bb = c & 1;
    u64 mrow0 = bits_t[(size_t)(split * 16 + c * 2)     * 4096 + i];   // coalesced
    u64 mrow1 = bits_t[(size_t)(split * 16 + c * 2 + 1) * 4096 + i];
    __syncthreads();                       // buf bb staged; buf bb^1 free
    if (c < 7) stage(bb ^ 1, jbeg + (c + 1) * 128);
    #pragma unroll
    for (int ks = 0; ks < 4; ++ks){
      uint4 e1q = *(const uint4*)((const char*)&smT[bb][0][0] + ks * 64 + grp * 16);
      uint4 e2q = *(const uint4*)((const char*)&smT[bb][1][0] + ks * 64 + grp * 16);
      u32 es[4] = {e1q.x, e1q.y, e1q.z, e1q.w};
      u32 gs[4] = {e2q.x, e2q.y, e2q.z, e2q.w};
      const u16* bbase = &smB[bb][(ks * 4 + grp) * 512];
      half8 bf0 = *(const half8*)(bbase + (0 * 16 + row16) * 8);
      half8 bf1 = *(const half8*)(bbase + (1 * 16 + row16) * 8);
      half8 bf2 = *(const half8*)(bbase + (2 * 16 + row16) * 8);
      half8 bf3 = *(const half8*)(bbase + (3 * 16 + row16) * 8);
      u64 mrow = (ks < 2) ? mrow0 : mrow1;
      u32 mb = ((u32)(mrow >> ((ks & 1) * 32)) >> (grp * 8)) & 0xffu;
      u32 pk[4];
      #pragma unroll
      for (int t2i = 0; t2i < 4; ++t2i){
        h2 w = __builtin_elementwise_max(u2h2(es[t2i]), rr * u2h2(gs[t2i]));
        pk[t2i] = h22u(w) & smLut[(mb >> (2 * t2i)) & 3u];
      }
      half8 af = pk2h8(*(uint4*)pk);
      acc[0] = __builtin_amdgcn_mfma_f32_16x16x32_f16(af, bf0, acc[0], 0, 0, 0);
      acc[1] = __builtin_amdgcn_mfma_f32_16x16x32_f16(af, bf1, acc[1], 0, 0, 0);
      acc[2] = __builtin_amdgcn_mfma_f32_16x16x32_f16(af, bf2, acc[2], 0, 0, 0);
      acc[3] = __builtin_amdgcn_mfma_f32_16x16x32_f16(af, bf3, acc[3], 0, 0, 0);
      accden = __builtin_amdgcn_mfma_f32_16x16x32_f16(af, bden, accden, 0, 0, 0);
    }
  }

  #pragma unroll
  for (int r4 = 0; r4 < 4; ++r4){
    int n = iblk * 64 + wv * 16 + grp * 4 + r4;
    if (row16 == 0)
      pden[((size_t)split * 8 + h) * 4096 + n] = accden[r4];
    u16* dst = pnum + ((size_t)split * 4096 + n) * 512 + h * 64 + row16;
    #pragma unroll
    for (int nt = 0; nt < 4; ++nt)
      dst[nt * 16] = f2h(acc[nt][r4]);
  }
}

// ===== K3: combine + Who = h @ Wout + layer-2 tables (4 rows/block) ========
__global__ __launch_bounds__(256) void k_gemm2(const u16* __restrict__ pnum,
                                               const float* __restrict__ pden,
                                               const float* __restrict__ Wout,
                                               const float* __restrict__ aout,
                                               u16* __restrict__ whoB,
                                               float* __restrict__ r1o,
                                               u16* __restrict__ e21oh, u16* __restrict__ e202oh){
  __shared__ float hrowf[4][512];             // 8 KB combined+elu rows (f32)
  int n0  = blockIdx.x * 4;
  int tid = threadIdx.x;
  // ---- phase A: combine 4 splits + ELU, 64 threads per row ----
  {
    int nn = tid >> 6;                        // row 0..3
    int fc = tid & 63;                        // f-chunk 0..63
    int f0 = fc * 8;
    int hh = fc >> 3;                         // head = f0/64
    int n  = n0 + nn;
    float v[8] = {0.f,0.f,0.f,0.f,0.f,0.f,0.f,0.f};
    float d = 0.f;
    #pragma unroll
    for (int s = 0; s < 4; ++s){
      uint4 raw = *(const uint4*)(pnum + ((size_t)s * 4096 + n) * 512 + f0);
      u32 rw[4] = {raw.x, raw.y, raw.z, raw.w};
      #pragma unroll
      for (int q = 0; q < 4; ++q){
        h2 dh = u2h2(rw[q]);
        v[q * 2]     += (float)dh.x;
        v[q * 2 + 1] += (float)dh.y;
      }
      d += pden[((size_t)s * 8 + hh) * 4096 + n];
    }
    float dinv = 1.f / d;
    #pragma unroll
    for (int k = 0; k < 8; ++k){
      float val = v[k] * dinv;
      hrowf[nn][f0 + k] = val > 0.f ? val : (__expf(val) - 1.f);
    }
  }
  __syncthreads();
  // ---- phase B: who[n][c] via K-split dot (Wout stays in L1: 32 KB) ----
  int rl = tid >> 6;                          // row 0..3
  int kq = (tid >> 4) & 3;                    // K-quarter 0..3
  int c  = tid & 15;                          // out col 0..15
  int n  = n0 + rl;
  const float* hr = &hrowf[rl][kq * 128];
  const float* wp = Wout + (size_t)(kq * 128) * 16 + c;
  float a0 = 0.f, a1 = 0.f;
  #pragma unroll 16
  for (int f = 0; f < 128; f += 2){
    a0 += hr[f]     * wp[f * 16];
    a1 += hr[f + 1] * wp[f * 16 + 16];
  }
  float acc = a0 + a1;
  acc += __shfl_xor(acc, 16, 64);             // reduce over kq
  acc += __shfl_xor(acc, 32, 64);
  int lane = tid & 63;
  if ((lane >> 4) == 0)
    whoB[((size_t)(n >> 3) * 16 + c) * 8 + (n & 7)] = f2h(acc);
  float p1 = acc * aout[c], p2 = acc * aout[16 + c];
  #pragma unroll
  for (int d = 1; d < 16; d <<= 1){ p1 += __shfl_xor(p1, d, 64); p2 += __shfl_xor(p2, d, 64); }
  if (lane == 0){
    r1o[n]    = __expf(-0.8f * p1);
    e21oh[n]  = f2h(__expf(p2));
    e202oh[n] = f2h(__expf(0.2f * p2));
  }
}

// ===== K4: layer-2 attention (16-way split, f16, global-direct) ============
__global__ __launch_bounds__(256) void k_att2(const u16* __restrict__ whoB,
                                              const u64* __restrict__ bits_t,
                                              const float* __restrict__ r1o,
                                              const u16* __restrict__ e21oh, const u16* __restrict__ e202oh,
                                              float* __restrict__ pnum, float* __restrict__ pden){
  __shared__ u32 smLut[4];
  int iblk  = blockIdx.x;
  int split = blockIdx.y;                     // 0..15
  int lane = threadIdx.x & 63;
  int wv   = threadIdx.x >> 6;
  int row16 = lane & 15, grp = lane >> 4;
  if (threadIdx.x < 4)
    smLut[threadIdx.x] = ((threadIdx.x & 1) ? 0xFFFFu : 0u) | ((threadIdx.x & 2) ? 0xFFFF0000u : 0u);
  __syncthreads();
  int i = iblk * 64 + wv * 16 + row16;
  u32 rb = (u32)f2h(r1o[i]); rb |= rb << 16;
  h2 rr = u2h2(rb);
  int jbeg = split * 256;
  half8 bden;
  {
    u32 z[4] = {0,0,0,0};
    if (row16 == 0){ z[0]=0x3C003C00u; z[1]=0x3C003C00u; z[2]=0x3C003C00u; z[3]=0x3C003C00u; }
    bden = pk2h8(*(uint4*)z);
  }

  f32x4 acc = {};
  f32x4 accden = {};
  #pragma unroll
  for (int c = 0; c < 4; ++c){
    int j0 = jbeg + c * 64;
    u64 mrow = bits_t[(size_t)(split * 4 + c) * 4096 + i];   // coalesced
    #pragma unroll
    for (int ks = 0; ks < 2; ++ks){
      int sb = (j0 >> 3) + ks * 4 + grp;
      half8 bf = *(const half8*)(whoB + ((size_t)sb * 16 + row16) * 8);
      uint4 e1q = *(const uint4*)(e21oh  + j0 + ks * 32 + grp * 8);
      uint4 e2q = *(const uint4*)(e202oh + j0 + ks * 32 + grp * 8);
      u32 es[4] = {e1q.x, e1q.y, e1q.z, e1q.w};
      u32 gs[4] = {e2q.x, e2q.y, e2q.z, e2q.w};
      u32 mb = ((u32)(mrow >> (ks * 32)) >> (grp * 8)) & 0xffu;
      u32 pk[4];
      #pragma unroll
      for (int t2i = 0; t2i < 4; ++t2i){
        h2 w = __builtin_elementwise_max(u2h2(es[t2i]), rr * u2h2(gs[t2i]));
        pk[t2i] = h22u(w) & smLut[(mb >> (2 * t2i)) & 3u];
      }
      half8 af = pk2h8(*(uint4*)pk);
      acc    = __builtin_amdgcn_mfma_f32_16x16x32_f16(af, bf, acc, 0, 0, 0);
      accden = __builtin_amdgcn_mfma_f32_16x16x32_f16(af, bden, accden, 0, 0, 0);
    }
  }
  #pragma unroll
  for (int r4 = 0; r4 < 4; ++r4){
    int n = iblk * 64 + wv * 16 + grp * 4 + r4;
    if (row16 == 0)
      pden[(size_t)n * 16 + split] = accden[r4];
    pnum[((size_t)n * 16 + split) * 16 + row16] = acc[r4];
  }
}

// ===== K5: combine + elu + log_softmax =====================================
__global__ __launch_bounds__(256) void k_final(const float* __restrict__ pnum,
                                               const float* __restrict__ pden,
                                               float* __restrict__ out){
  int tid = blockIdx.x * 256 + threadIdx.x;   // 65536
  int c = tid & 15;
  int n = tid >> 4;
  float num = 0.f, den = 0.f;
  #pragma unroll
  for (int s = 0; s < 16; ++s){
    num += pnum[((size_t)n * 16 + s) * 16 + c];
    den += pden[(size_t)n * 16 + s];
  }
  float v = num / den;
  v = v > 0.f ? v : (__expf(v) - 1.f);
  float m = v;
  #pragma unroll
  for (int d = 1; d < 16; d <<= 1) m = fmaxf(m, __shfl_xor(m, d, 64));
  float es = __expf(v - m), ss = es;
  #pragma unroll
  for (int d = 1; d < 16; d <<= 1) ss += __shfl_xor(ss, d, 64);
  out[(size_t)n * 16 + c] = v - m - __logf(ss);
}

// ---------------------------------------------------------------------------
extern "C" void kernel_launch(void* const* d_in, const int* in_sizes, int n_in,
                              void* d_out, int out_size, void* d_ws, size_t ws_size,
                              hipStream_t stream){
  (void)in_sizes; (void)n_in; (void)out_size; (void)ws_size;
  const float* x    = (const float*)d_in[0];
  const int*   adj  = (const int*)d_in[1];
  const float* W    = (const float*)d_in[2];
  const float* av   = (const float*)d_in[3];
  const float* Wout = (const float*)d_in[4];
  const float* aout = (const float*)d_in[5];
  float* out = (float*)d_out;
  char* ws = (char*)d_ws;

  u64*  bits_t  = (u64*)(ws + 0x0000000);        // 2 MB [64][4096]
  u16*  whB     = (u16*)(ws + 0x0200000);        // 4 MB f16 [8][j/8][o][8]
  float* r1     = (float*)(ws + 0x0600000);      // 128 KB
  u16*  e21h    = (u16*)(ws + 0x0620000);        // 64 KB f16
  u16*  e202h   = (u16*)(ws + 0x0630000);        // 64 KB f16
  u16*  pnum1   = (u16*)(ws + 0x0680000);        // 16 MB f16 [4][4096][512]
  float* pden1  = (float*)(ws + 0x1680000);      // 512 KB [4][8][4096]
  u16*  whoB    = (u16*)(ws + 0x1700000);        // 128 KB f16
  float* r1o    = (float*)(ws + 0x1720000);      // 16 KB
  u16*  e21oh   = (u16*)(ws + 0x1724000);        // 8 KB f16
  u16*  e202oh  = (u16*)(ws + 0x1726000);        // 8 KB f16
  float* pnum2  = (float*)(ws + 0x1730000);      // 4 MB [4096][16][16]
  float* pden2  = (float*)(ws + 0x1B30000);      // 256 KB
  // Wb16 aliases pnum2's region: written by k_wpack, consumed by k_gemm1,
  // then dead before k_att2 overwrites the region (stream-ordered safe).
  u16*  Wb16    = (u16*)(ws + 0x1730000);        // 512 KB f16 [8][64][64][8]

  k_wpack<<<dim3(128), dim3(256), 0, stream>>>(W, Wb16);
  k_gemm1<<<dim3(128, 8), dim3(256), 0, stream>>>(x, Wb16, av, adj, whB, bits_t, r1, e21h, e202h);
  k_att1<<<dim3(64, 8, 4), dim3(256), 0, stream>>>(whB, bits_t, r1, e21h, e202h, pnum1, pden1);
  k_gemm2<<<dim3(1024), dim3(256), 0, stream>>>(pnum1, pden1, Wout, aout, whoB, r1o, e21oh, e202oh);
  k_att2<<<dim3(64, 16), dim3(256), 0, stream>>>(whoB, bits_t, r1o, e21oh, e202oh, pnum2, pden2);
  k_final<<<dim3(256), dim3(256), 0, stream>>>(pnum2, pden2, out);
}